// Round 1
// 215.379 us; speedup vs baseline: 1.0382x; 1.0382x over previous
//
#include <hip/hip_runtime.h>
#include <math.h>

#define ROW_LEN 4096
#define NROWS   8192
#define BLOCK   256
#define WAVES_PER_BLOCK (BLOCK / 64)
// 4096 floats / 64 lanes = 64 floats/lane = 16 float4/lane
#define F4_PER_LANE 16

// native clang vector type — accepted by __builtin_nontemporal_load/store
typedef float vf4 __attribute__((ext_vector_type(4)));

__global__ __launch_bounds__(BLOCK) void masked_softmax_wave(
    const float* __restrict__ X,
    const int* __restrict__ N,
    float* __restrict__ out)
{
    const int wave = threadIdx.x >> 6;
    const int lane = threadIdx.x & 63;
    const int row  = blockIdx.x * WAVES_PER_BLOCK + wave;

    // n is wave-uniform (one row per wave) — force it scalar (SGPR) so all
    // per-chunk validity tests below compile to s_cmp + s_cbranch.
    const int n = __builtin_amdgcn_readfirstlane(N[row]);

    const vf4* __restrict__ Xr = (const vf4*)(X + (size_t)row * ROW_LEN);
    vf4* __restrict__ Or       = (vf4*)(out + (size_t)row * ROW_LEN);

    vf4 v[F4_PER_LANE];
    const vf4 z4 = {0.0f, 0.0f, 0.0f, 0.0f};

    // ---- load ONLY chunks containing valid columns ----
    // chunk j covers cols [256*j, 256*j+255] across the wave:
    //   256*j >= n        -> entirely dead: uniform scalar skip, no traffic
    //   else              -> lane-predicated load (exec-masked lanes fetch nothing)
    #pragma unroll
    for (int j = 0; j < F4_PER_LANE; j++) {
        v[j] = z4;
        if (256 * j < n) {                       // wave-uniform branch
            if (4 * (lane + 64 * j) < n)         // boundary predicate
                v[j] = __builtin_nontemporal_load(&Xr[lane + 64 * j]);
        }
    }

    // ---- masked max over registers ----
    // three-way split: fully-valid chunks need no per-element masks.
    float m = -INFINITY;
    #pragma unroll
    for (int j = 0; j < F4_PER_LANE; j++) {
        if (256 * (j + 1) <= n) {                // fully valid
            m = fmaxf(m, fmaxf(fmaxf(v[j].x, v[j].y), fmaxf(v[j].z, v[j].w)));
        } else if (256 * j < n) {                // boundary chunk
            const int col = 4 * (lane + 64 * j);
            m = fmaxf(m, (col + 0 < n) ? v[j].x : -INFINITY);
            m = fmaxf(m, (col + 1 < n) ? v[j].y : -INFINITY);
            m = fmaxf(m, (col + 2 < n) ? v[j].z : -INFINITY);
            m = fmaxf(m, (col + 3 < n) ? v[j].w : -INFINITY);
        }
        // dead chunks: skipped entirely
    }
    // wave-wide max, butterfly (no LDS, no barrier)
    #pragma unroll
    for (int off = 1; off < 64; off <<= 1)
        m = fmaxf(m, __shfl_xor(m, off, 64));

    // ---- exp (mask folded in; v[] becomes masked exp) + masked sum ----
    float s = 0.0f;
    #pragma unroll
    for (int j = 0; j < F4_PER_LANE; j++) {
        if (256 * (j + 1) <= n) {                // fully valid: no masks
            float ex = __expf(v[j].x - m);
            float ey = __expf(v[j].y - m);
            float ez = __expf(v[j].z - m);
            float ew = __expf(v[j].w - m);
            v[j].x = ex; v[j].y = ey; v[j].z = ez; v[j].w = ew;
            s += (ex + ey) + (ez + ew);
        } else if (256 * j < n) {                // boundary chunk
            const int col = 4 * (lane + 64 * j);
            float ex = __expf(v[j].x - m);
            float ey = __expf(v[j].y - m);
            float ez = __expf(v[j].z - m);
            float ew = __expf(v[j].w - m);
            ex = (col + 0 < n) ? ex : 0.0f;
            ey = (col + 1 < n) ? ey : 0.0f;
            ez = (col + 2 < n) ? ez : 0.0f;
            ew = (col + 3 < n) ? ew : 0.0f;
            v[j].x = ex; v[j].y = ey; v[j].z = ez; v[j].w = ew;
            s += (ex + ey) + (ez + ew);
        }
        // dead chunks: v[j] stays exactly zero
    }
    // wave-wide sum, butterfly
    #pragma unroll
    for (int off = 1; off < 64; off <<= 1)
        s += __shfl_xor(s, off, 64);

    const float inv = 1.0f / s;

    // ---- store FULL row (tail must be written as zeros), streamed ----
    #pragma unroll
    for (int j = 0; j < F4_PER_LANE; j++) {
        vf4 o = z4;
        if (256 * j < n) {                       // uniform: skip mul for dead chunks
            o.x = v[j].x * inv;
            o.y = v[j].y * inv;
            o.z = v[j].z * inv;
            o.w = v[j].w * inv;
        }
        __builtin_nontemporal_store(o, &Or[lane + 64 * j]);
    }
}

extern "C" void kernel_launch(void* const* d_in, const int* in_sizes, int n_in,
                              void* d_out, int out_size, void* d_ws, size_t ws_size,
                              hipStream_t stream) {
    const float* X = (const float*)d_in[0];
    const int*   N = (const int*)d_in[1];
    float* out = (float*)d_out;
    masked_softmax_wave<<<NROWS / WAVES_PER_BLOCK, BLOCK, 0, stream>>>(X, N, out);
}

// Round 2
// 213.324 us; speedup vs baseline: 1.0482x; 1.0096x over previous
//
#include <hip/hip_runtime.h>
#include <math.h>

#define ROW_LEN 4096
#define NROWS   8192
#define BLOCK   256
#define NWAVES  (BLOCK / 64)
// 4096 floats / 256 threads = 16 floats/thread = 4 float4/thread
#define F4_PER_LANE 4

// native clang vector type — accepted by __builtin_nontemporal_load/store
typedef float vf4 __attribute__((ext_vector_type(4)));

__global__ __launch_bounds__(BLOCK) void masked_softmax_block(
    const float* __restrict__ X,
    const int* __restrict__ N,
    float* __restrict__ out)
{
    const int tid  = threadIdx.x;
    const int wave = tid >> 6;
    const int lane = tid & 63;
    const int row  = blockIdx.x;          // one row per block

    // n is block-uniform — force it scalar so chunk tests are s_cmp/s_cbranch
    const int n = __builtin_amdgcn_readfirstlane(N[row]);

    const vf4* __restrict__ Xr = (const vf4*)(X + (size_t)row * ROW_LEN);
    vf4* __restrict__ Or       = (vf4*)(out + (size_t)row * ROW_LEN);

    __shared__ float redm[NWAVES];
    __shared__ float reds[NWAVES];

    vf4 v[F4_PER_LANE];
    const vf4 z4 = {0.0f, 0.0f, 0.0f, 0.0f};

    // ---- load ONLY chunks containing valid columns ----
    // chunk j covers cols [1024*j, 1024*j+1023] across the block:
    //   1024*j >= n -> uniform scalar skip, zero traffic
    //   else        -> lane-predicated load (exec-masked lanes fetch nothing)
    #pragma unroll
    for (int j = 0; j < F4_PER_LANE; j++) {
        v[j] = z4;
        if (1024 * j < n) {                      // block-uniform branch
            if (4 * (tid + 256 * j) < n)         // boundary predicate
                v[j] = __builtin_nontemporal_load(&Xr[tid + 256 * j]);
        }
    }

    // ---- masked max over registers (3-way split per chunk) ----
    float m = -INFINITY;
    #pragma unroll
    for (int j = 0; j < F4_PER_LANE; j++) {
        if (1024 * (j + 1) <= n) {               // fully valid: no masks
            m = fmaxf(m, fmaxf(fmaxf(v[j].x, v[j].y), fmaxf(v[j].z, v[j].w)));
        } else if (1024 * j < n) {               // boundary chunk
            const int col = 4 * (tid + 256 * j);
            m = fmaxf(m, (col + 0 < n) ? v[j].x : -INFINITY);
            m = fmaxf(m, (col + 1 < n) ? v[j].y : -INFINITY);
            m = fmaxf(m, (col + 2 < n) ? v[j].z : -INFINITY);
            m = fmaxf(m, (col + 3 < n) ? v[j].w : -INFINITY);
        }
        // dead chunks: skipped entirely
    }
    // wave butterfly max (no LDS), then 4-wave LDS combine
    #pragma unroll
    for (int off = 1; off < 64; off <<= 1)
        m = fmaxf(m, __shfl_xor(m, off, 64));
    if (lane == 0) redm[wave] = m;
    __syncthreads();
    m = fmaxf(fmaxf(redm[0], redm[1]), fmaxf(redm[2], redm[3]));

    // ---- exp (mask folded in; v[] becomes masked exp) + masked sum ----
    float s = 0.0f;
    #pragma unroll
    for (int j = 0; j < F4_PER_LANE; j++) {
        if (1024 * (j + 1) <= n) {               // fully valid: no masks
            float ex = __expf(v[j].x - m);
            float ey = __expf(v[j].y - m);
            float ez = __expf(v[j].z - m);
            float ew = __expf(v[j].w - m);
            v[j].x = ex; v[j].y = ey; v[j].z = ez; v[j].w = ew;
            s += (ex + ey) + (ez + ew);
        } else if (1024 * j < n) {               // boundary chunk
            const int col = 4 * (tid + 256 * j);
            float ex = __expf(v[j].x - m);
            float ey = __expf(v[j].y - m);
            float ez = __expf(v[j].z - m);
            float ew = __expf(v[j].w - m);
            ex = (col + 0 < n) ? ex : 0.0f;
            ey = (col + 1 < n) ? ey : 0.0f;
            ez = (col + 2 < n) ? ez : 0.0f;
            ew = (col + 3 < n) ? ew : 0.0f;
            v[j].x = ex; v[j].y = ey; v[j].z = ez; v[j].w = ew;
            s += (ex + ey) + (ez + ew);
        }
        // dead chunks: v[j] stays exactly zero
    }
    // wave butterfly sum, then 4-wave LDS combine
    #pragma unroll
    for (int off = 1; off < 64; off <<= 1)
        s += __shfl_xor(s, off, 64);
    if (lane == 0) reds[wave] = s;
    __syncthreads();
    s = (reds[0] + reds[1]) + (reds[2] + reds[3]);

    const float inv = 1.0f / s;

    // ---- store FULL row (tail must be written as zeros), streamed ----
    #pragma unroll
    for (int j = 0; j < F4_PER_LANE; j++) {
        vf4 o = z4;
        if (1024 * j < n) {                      // uniform: skip mul for dead chunks
            o.x = v[j].x * inv;
            o.y = v[j].y * inv;
            o.z = v[j].z * inv;
            o.w = v[j].w * inv;
        }
        __builtin_nontemporal_store(o, &Or[tid + 256 * j]);
    }
}

extern "C" void kernel_launch(void* const* d_in, const int* in_sizes, int n_in,
                              void* d_out, int out_size, void* d_ws, size_t ws_size,
                              hipStream_t stream) {
    const float* X = (const float*)d_in[0];
    const int*   N = (const int*)d_in[1];
    float* out = (float*)d_out;
    masked_softmax_block<<<NROWS, BLOCK, 0, stream>>>(X, N, out);
}

// Round 3
// 211.882 us; speedup vs baseline: 1.0553x; 1.0068x over previous
//
#include <hip/hip_runtime.h>
#include <math.h>

#define ROW_LEN 4096
#define NROWS   8192
#define BLOCK   256
#define NWAVES  (BLOCK / 64)
// 4096 floats / 256 threads = 16 floats/thread = 4 float4/thread
#define F4_PER_LANE 4

// native clang vector type — accepted by __builtin_nontemporal_load/store
typedef float vf4 __attribute__((ext_vector_type(4)));

__global__ __launch_bounds__(BLOCK) void masked_softmax_block(
    const float* __restrict__ X,
    const int* __restrict__ N,
    float* __restrict__ out)
{
    const int tid  = threadIdx.x;
    const int wave = tid >> 6;
    const int lane = tid & 63;
    const int row  = blockIdx.x;          // one row per block

    // n is block-uniform — force it scalar so chunk tests are s_cmp/s_cbranch
    const int n = __builtin_amdgcn_readfirstlane(N[row]);

    const vf4* __restrict__ Xr = (const vf4*)(X + (size_t)row * ROW_LEN);
    vf4* __restrict__ Or       = (vf4*)(out + (size_t)row * ROW_LEN);

    __shared__ float redm[NWAVES];
    __shared__ float reds[NWAVES];

    vf4 v[F4_PER_LANE];
    const vf4 z4 = {0.0f, 0.0f, 0.0f, 0.0f};

    // ---- issue loads for live chunks FIRST (critical path) ----
    // chunk j covers cols [1024*j, 1024*j+1023] across the block:
    //   1024*j >= n -> uniform scalar skip, zero traffic
    //   else        -> lane-predicated load (exec-masked lanes fetch nothing)
    #pragma unroll
    for (int j = 0; j < F4_PER_LANE; j++) {
        v[j] = z4;
        if (1024 * j < n) {                      // block-uniform branch
            if (4 * (tid + 256 * j) < n)         // boundary predicate
                v[j] = __builtin_nontemporal_load(&Xr[tid + 256 * j]);
        }
    }

    // ---- EARLY tail-zero stores for fully-dead chunks ----
    // These depend only on n — issue them now so ~half the write stream
    // overlaps the read/compute phase instead of trailing it.
    // Plain (cached) stores: let L2/L3 absorb and write back lazily.
    #pragma unroll
    for (int j = 0; j < F4_PER_LANE; j++) {
        if (1024 * j >= n) {                     // block-uniform branch
            Or[tid + 256 * j] = z4;
        }
    }

    // ---- masked max over registers (3-way split per chunk) ----
    float m = -INFINITY;
    #pragma unroll
    for (int j = 0; j < F4_PER_LANE; j++) {
        if (1024 * (j + 1) <= n) {               // fully valid: no masks
            m = fmaxf(m, fmaxf(fmaxf(v[j].x, v[j].y), fmaxf(v[j].z, v[j].w)));
        } else if (1024 * j < n) {               // boundary chunk
            const int col = 4 * (tid + 256 * j);
            m = fmaxf(m, (col + 0 < n) ? v[j].x : -INFINITY);
            m = fmaxf(m, (col + 1 < n) ? v[j].y : -INFINITY);
            m = fmaxf(m, (col + 2 < n) ? v[j].z : -INFINITY);
            m = fmaxf(m, (col + 3 < n) ? v[j].w : -INFINITY);
        }
        // dead chunks: skipped entirely
    }
    // wave butterfly max (no LDS), then 4-wave LDS combine
    #pragma unroll
    for (int off = 1; off < 64; off <<= 1)
        m = fmaxf(m, __shfl_xor(m, off, 64));
    if (lane == 0) redm[wave] = m;
    __syncthreads();
    m = fmaxf(fmaxf(redm[0], redm[1]), fmaxf(redm[2], redm[3]));

    // ---- exp (mask folded in; v[] becomes masked exp) + masked sum ----
    float s = 0.0f;
    #pragma unroll
    for (int j = 0; j < F4_PER_LANE; j++) {
        if (1024 * (j + 1) <= n) {               // fully valid: no masks
            float ex = __expf(v[j].x - m);
            float ey = __expf(v[j].y - m);
            float ez = __expf(v[j].z - m);
            float ew = __expf(v[j].w - m);
            v[j].x = ex; v[j].y = ey; v[j].z = ez; v[j].w = ew;
            s += (ex + ey) + (ez + ew);
        } else if (1024 * j < n) {               // boundary chunk
            const int col = 4 * (tid + 256 * j);
            float ex = __expf(v[j].x - m);
            float ey = __expf(v[j].y - m);
            float ez = __expf(v[j].z - m);
            float ew = __expf(v[j].w - m);
            ex = (col + 0 < n) ? ex : 0.0f;
            ey = (col + 1 < n) ? ey : 0.0f;
            ez = (col + 2 < n) ? ez : 0.0f;
            ew = (col + 3 < n) ? ew : 0.0f;
            v[j].x = ex; v[j].y = ey; v[j].z = ez; v[j].w = ew;
            s += (ex + ey) + (ez + ew);
        }
        // dead chunks: v[j] stays exactly zero (never stored here)
    }
    // wave butterfly sum, then 4-wave LDS combine
    #pragma unroll
    for (int off = 1; off < 64; off <<= 1)
        s += __shfl_xor(s, off, 64);
    if (lane == 0) reds[wave] = s;
    __syncthreads();
    s = (reds[0] + reds[1]) + (reds[2] + reds[3]);

    const float inv = 1.0f / s;

    // ---- store live chunks (tail chunks already written above) ----
    // Plain (cached) stores — L2/L3 absorbs the stream.
    #pragma unroll
    for (int j = 0; j < F4_PER_LANE; j++) {
        if (1024 * j < n) {                      // uniform: dead chunks done early
            vf4 o;
            o.x = v[j].x * inv;
            o.y = v[j].y * inv;
            o.z = v[j].z * inv;
            o.w = v[j].w * inv;
            Or[tid + 256 * j] = o;
        }
    }
}

extern "C" void kernel_launch(void* const* d_in, const int* in_sizes, int n_in,
                              void* d_out, int out_size, void* d_ws, size_t ws_size,
                              hipStream_t stream) {
    const float* X = (const float*)d_in[0];
    const int*   N = (const int*)d_in[1];
    float* out = (float*)d_out;
    masked_softmax_block<<<NROWS, BLOCK, 0, stream>>>(X, N, out);
}